// Round 4
// baseline (493.908 us; speedup 1.0000x reference)
//
#include <hip/hip_runtime.h>
#include <hip/hip_bf16.h>

typedef short short8 __attribute__((ext_vector_type(8)));
typedef float floatx4 __attribute__((ext_vector_type(4)));

constexpr int Bn = 128, Tn = 2048, DPn = 256, DQn = 256, DOn = 256;
constexpr int NPART = 4;            // T-quarters per batch row
constexpr int NITER = 16;           // chunks per block
constexpr int CR = 32;              // rows per chunk

__device__ inline unsigned pk2(float x, float y) {
    __hip_bfloat162 h = __float22bfloat162_rn(make_float2(x, y));
    return *(unsigned*)&h;
}
__device__ inline float bf2f(unsigned short h) {
    return __uint_as_float(((unsigned)h) << 16);
}
__device__ inline float fast_tanh(float x) {
    float e = __expf(2.0f * x);
    return 1.0f - 2.0f / (e + 1.0f);
}

// ---------------- Kernel 0: W_q (fp32 [DO,DQ]) -> bf16 ----------------
__global__ __launch_bounds__(256) void cvt_wq_kernel(const float* __restrict__ wq,
                                                     unsigned short* __restrict__ wqbf) {
    int idx = blockIdx.x * 256 + threadIdx.x;
    float4 v = ((const float4*)wq)[idx];
    ((uint2*)wqbf)[idx] = make_uint2(pk2(v.x, v.y), pk2(v.z, v.w));
}

// ---------------- Kernel 1: base[b][d] = W_p_r[d]·[input_p[b],h[b]] + b_p_r[d] + b_q[d] ----------------
__global__ __launch_bounds__(256) void base_kernel(const float* __restrict__ input_p,
                                                   const float* __restrict__ h_tm1,
                                                   const float* __restrict__ Wpr,
                                                   const float* __restrict__ bpr,
                                                   const float* __restrict__ bq,
                                                   float* __restrict__ base) {
    __shared__ float v[512];
    int b = blockIdx.x, tid = threadIdx.x;
    v[tid]       = input_p[b * DPn + tid];
    v[256 + tid] = h_tm1[b * DOn + tid];
    __syncthreads();
    const float4* row = (const float4*)(Wpr + (size_t)tid * 512);
    const float4* vv  = (const float4*)v;
    float acc = 0.f;
#pragma unroll 8
    for (int i = 0; i < 128; i++) {
        float4 r = row[i], x = vv[i];
        acc = fmaf(r.x, x.x, acc);
        acc = fmaf(r.y, x.y, acc);
        acc = fmaf(r.z, x.z, acc);
        acc = fmaf(r.w, x.w, acc);
    }
    base[b * DOn + tid] = acc + bpr[tid] + bq[tid];
}

// ---------------- Kernel 2 (persistent, double-buffered) ----------------
// grid (4, 128): block = (t-quarter p, b). 512 blocks = exactly 2/CU resident.
// Loops 16 chunks of 32 t-rows: prefetch chunk i+1 to regs at iter top,
// MFMA logits + e' + znum(register-accumulated) on chunk i from LDS bf16
// panels, cvt+ds_write chunk i+1 into the other buffer at iter bottom.
// All LDS panel accesses are at the structural b128 minimum (8 lanes/group).
__global__ __launch_bounds__(256, 2) void attn_kernel(const float* __restrict__ q,
                                                      const unsigned short* __restrict__ wqbf,
                                                      const float* __restrict__ base,
                                                      const float* __restrict__ wvec,
                                                      const float* __restrict__ matchb,
                                                      const int* __restrict__ maskq,
                                                      float* __restrict__ zpart,
                                                      float* __restrict__ spart,
                                                      float* __restrict__ mpart) {
    // panels[buf][mt*8+ks][slot=quad*16+l15][8 bf16]: frag-contiguous, 16 KB/buf
    __shared__ __align__(16) unsigned short panels[2][16][64][8];
    __shared__ float partl[4][32];
    __shared__ float earr[32];
    __shared__ float zp[8][256];

    int p = blockIdx.x, b = blockIdx.y;
    int tid = threadIdx.x, w = tid >> 6, lane = tid & 63;
    int l15 = lane & 15, quad = lane >> 4;
    int tbase = p * (Tn / NPART);

    // ---- persistent B fragments + per-n scalars (loaded once) ----
    short8 bfr[4][8];
    const unsigned short* bbase = wqbf + (size_t)(w * 64 + l15) * 256 + quad * 8;
#pragma unroll
    for (int nt = 0; nt < 4; nt++)
#pragma unroll
        for (int ks = 0; ks < 8; ks++)
            bfr[nt][ks] = *(const short8*)(bbase + nt * 16 * 256 + ks * 32);
    float bn[4], wn[4];
#pragma unroll
    for (int nt = 0; nt < 4; nt++) {
        int n = w * 64 + nt * 16 + l15;
        bn[nt] = base[b * DOn + n];
        wn[nt] = wvec[n];
    }
    float mb = matchb[0];

    // staging lane mapping: row srow = w*8 + rw, float4-slots k*16 + c0*2 + {0,1}
    int c0 = lane & 7, rw = lane >> 3;
    int srow = w * 8 + rw;
    int smt = srow >> 4, ss = srow & 15;

    // znum lane mapping: octet zo, row-group zws (rows zws*4 + ((j+zo)&3))
    int zo = tid & 31, zws = tid >> 5;

    float zacc[8] = {0.f, 0.f, 0.f, 0.f, 0.f, 0.f, 0.f, 0.f};
    float sacc = 0.f, macc = -1e30f;   // meaningful for tid<32

    float4 pf[8];
    // ---- prologue: load + stage chunk 0 into buf 0 ----
    {
        const float4* qrow = (const float4*)(q + ((size_t)b * Tn + tbase + srow) * DQn);
#pragma unroll
        for (int k = 0; k < 4; k++) {
            pf[2 * k]     = qrow[k * 16 + c0 * 2];
            pf[2 * k + 1] = qrow[k * 16 + c0 * 2 + 1];
        }
#pragma unroll
        for (int k = 0; k < 4; k++) {
            int o = k * 8 + c0;
            uint4 u;
            u.x = pk2(pf[2 * k].x, pf[2 * k].y);
            u.y = pk2(pf[2 * k].z, pf[2 * k].w);
            u.z = pk2(pf[2 * k + 1].x, pf[2 * k + 1].y);
            u.w = pk2(pf[2 * k + 1].z, pf[2 * k + 1].w);
            *(uint4*)&panels[0][smt * 8 + (o >> 2)][(o & 3) * 16 + ss][0] = u;
        }
    }

    for (int it = 0; it < NITER; ++it) {
        int cur = it & 1, nxt = cur ^ 1;
        __syncthreads();   // A: staging of cur visible; prev readers of nxt done

        // issue prefetch for chunk it+1 (hidden under MFMA+znum)
        if (it + 1 < NITER) {
            const float4* qrow =
                (const float4*)(q + ((size_t)b * Tn + tbase + (it + 1) * CR + srow) * DQn);
#pragma unroll
            for (int k = 0; k < 4; k++) {
                pf[2 * k]     = qrow[k * 16 + c0 * 2];
                pf[2 * k + 1] = qrow[k * 16 + c0 * 2 + 1];
            }
        }

        // ---- MFMA logits on chunk it ----
#pragma unroll
        for (int mt = 0; mt < 2; mt++) {
            short8 af[8];
#pragma unroll
            for (int ks = 0; ks < 8; ks++)
                af[ks] = *(const short8*)&panels[cur][mt * 8 + ks][quad * 16 + l15][0];
            float prow[4] = {0.f, 0.f, 0.f, 0.f};
#pragma unroll
            for (int nt = 0; nt < 4; nt++) {
                floatx4 acc = {0.f, 0.f, 0.f, 0.f};
#pragma unroll
                for (int ks = 0; ks < 8; ks++)
                    acc = __builtin_amdgcn_mfma_f32_16x16x32_bf16(af[ks], bfr[nt][ks], acc, 0, 0, 0);
#pragma unroll
                for (int r = 0; r < 4; r++) {
                    float g = fast_tanh(acc[r] + bn[nt]);
                    prow[r] = fmaf(g, wn[nt], prow[r]);
                }
            }
#pragma unroll
            for (int off = 1; off < 16; off <<= 1)
#pragma unroll
                for (int r = 0; r < 4; r++) prow[r] += __shfl_xor(prow[r], off);
            if (l15 == 0) {
#pragma unroll
                for (int r = 0; r < 4; r++) partl[w][mt * 16 + quad * 4 + r] = prow[r];
            }
        }
        __syncthreads();   // B

        // ---- e' for this chunk (exact masked-softmax bookkeeping) ----
        if (tid < CR) {
            float lg = partl[0][tid] + partl[1][tid] + partl[2][tid] + partl[3][tid] + mb;
            float m = (float)maskq[(size_t)b * Tn + tbase + it * CR + tid];
            float x = fminf(fmaxf(lg, -15.f), 15.f) * m;
            float e = __expf(x - 15.f) * m;
            earr[tid] = e;
            sacc += e;
            macc = fmaxf(macc, x);
        }
        __syncthreads();   // C

        // ---- znum accumulate from LDS panels (bank-staggered) ----
#pragma unroll
        for (int j = 0; j < 4; j++) {
            int row = zws * 4 + ((j + zo) & 3);
            int mt = row >> 4, s = row & 15;
            short8 f = *(const short8*)&panels[cur][mt * 8 + (zo >> 2)][(zo & 3) * 16 + s][0];
            float e = earr[row];
#pragma unroll
            for (int x = 0; x < 8; x++)
                zacc[x] = fmaf(e, bf2f((unsigned short)f[x]), zacc[x]);
        }

        // ---- stage chunk it+1 into nxt ----
        if (it + 1 < NITER) {
#pragma unroll
            for (int k = 0; k < 4; k++) {
                int o = k * 8 + c0;
                uint4 u;
                u.x = pk2(pf[2 * k].x, pf[2 * k].y);
                u.y = pk2(pf[2 * k].z, pf[2 * k].w);
                u.z = pk2(pf[2 * k + 1].x, pf[2 * k + 1].y);
                u.w = pk2(pf[2 * k + 1].z, pf[2 * k + 1].w);
                *(uint4*)&panels[nxt][smt * 8 + (o >> 2)][(o & 3) * 16 + ss][0] = u;
            }
        }
    }

    // ---- epilogue: combine z partials, write once per block ----
    __syncthreads();
    {
        float* zr = &zp[zws][zo * 8];
        *(float4*)(zr)     = make_float4(zacc[0], zacc[1], zacc[2], zacc[3]);
        *(float4*)(zr + 4) = make_float4(zacc[4], zacc[5], zacc[6], zacc[7]);
    }
    __syncthreads();
    {
        float zs = 0.f;
#pragma unroll
        for (int g = 0; g < 8; g++) zs += zp[g][tid];
        zpart[((size_t)b * NPART + p) * DQn + tid] = zs;
    }
    if (tid < CR) {
        float S = sacc, M = macc;
#pragma unroll
        for (int off = 1; off < 32; off <<= 1) {
            S += __shfl_xor(S, off);
            M = fmaxf(M, __shfl_xor(M, off));
        }
        if (tid == 0) {
            spart[b * NPART + p] = S;
            mpart[b * NPART + p] = M;
        }
    }
}

// ---------------- Kernel 3: exact denom + combine + concat ----------------
// z = (Σ_p znum_p) / (S' + 1e-6 * exp(mx - 15))  — identical to reference softmax math.
__global__ __launch_bounds__(256) void final_kernel(const float* __restrict__ input_p,
                                                    const float* __restrict__ zpart,
                                                    const float* __restrict__ spart,
                                                    const float* __restrict__ mpart,
                                                    float* __restrict__ out) {
    int b = blockIdx.x, tid = threadIdx.x;
    float S = 0.f, mx = -1e30f;
#pragma unroll
    for (int c = 0; c < NPART; c++) {
        S += spart[b * NPART + c];
        mx = fmaxf(mx, mpart[b * NPART + c]);
    }
    float inv = 1.0f / (S + 1e-6f * __expf(mx - 15.f));
    float zs = 0.f;
#pragma unroll
    for (int c = 0; c < NPART; c++) zs += zpart[((size_t)b * NPART + c) * DQn + tid];
    out[(size_t)b * 512 + tid] = input_p[(size_t)b * DPn + tid];
    out[(size_t)b * 512 + 256 + tid] = zs * inv;
}

extern "C" void kernel_launch(void* const* d_in, const int* in_sizes, int n_in,
                              void* d_out, int out_size, void* d_ws, size_t ws_size,
                              hipStream_t stream) {
    const float* input_p = (const float*)d_in[0];
    // d_in[1] = mask_p (unused by reference)
    const float* input_q = (const float*)d_in[2];
    const int*   mask_q  = (const int*)d_in[3];
    const float* h_tm1   = (const float*)d_in[4];
    const float* W_p_r   = (const float*)d_in[5];
    const float* b_p_r   = (const float*)d_in[6];
    const float* W_q     = (const float*)d_in[7];
    const float* b_q     = (const float*)d_in[8];
    const float* w       = (const float*)d_in[9];
    const float* match_b = (const float*)d_in[10];
    // d_in[11] = depth (unused, layer 0)
    float* out = (float*)d_out;

    char* ws = (char*)d_ws;
    unsigned short* wqbf = (unsigned short*)ws;               // 128 KiB
    float* base  = (float*)(ws + 131072);                     // 128 KiB
    float* zpart = (float*)(ws + 262144);                     // 128*4*256*4 = 512 KiB
    float* spart = (float*)(ws + 262144 + 524288);            // 2 KiB
    float* mpart = (float*)(ws + 262144 + 524288 + 8192);     // 2 KiB

    cvt_wq_kernel<<<64, 256, 0, stream>>>(W_q, wqbf);
    base_kernel<<<Bn, 256, 0, stream>>>(input_p, h_tm1, W_p_r, b_p_r, b_q, base);
    attn_kernel<<<dim3(NPART, Bn), 256, 0, stream>>>(input_q, wqbf, base, w, match_b,
                                                     mask_q, zpart, spart, mpart);
    final_kernel<<<Bn, 256, 0, stream>>>(input_p, zpart, spart, mpart, out);
}